// Round 3
// baseline (179.539 us; speedup 1.0000x reference)
//
#include <hip/hip_runtime.h>
#include <stdint.h>

#define BB 64
#define TT 512
#define HH 768

template <int CTRL>
__device__ __forceinline__ float dppf(float x) {
  return __int_as_float(__builtin_amdgcn_update_dpp(
      0, __float_as_int(x), CTRL, 0xF, 0xF, true));
}

// ---------------------------------------------------------------------------
// Kernel 1: emissions[row*4+k] = dot(sent[row,:], W[k,:]) + bias[k]
// Wave per row; lane l owns float4 #l of each 1KB chunk (3 chunks of 256
// floats). 4 rows per wave, 8192 waves -> 8 waves/SIMD for latency hiding.
// ---------------------------------------------------------------------------
__global__ __launch_bounds__(256) void emis_kernel(
    const float* __restrict__ sent, const float* __restrict__ W,
    const float* __restrict__ bias, float* __restrict__ emis) {
  const int lane  = threadIdx.x & 63;
  const int wave  = threadIdx.x >> 6;
  const int gwave = blockIdx.x * 4 + wave;   // 0..8191

  const float4* Wv = (const float4*)W;
  float4 w[4][3];
#pragma unroll
  for (int k = 0; k < 4; ++k)
#pragma unroll
    for (int c = 0; c < 3; ++c) w[k][c] = Wv[k * 192 + c * 64 + lane];

  const float4 bb = ((const float4*)bias)[0];
  const float4* sv = (const float4*)sent;

  int row = gwave * 4;
  float4 x[3];
#pragma unroll
  for (int c = 0; c < 3; ++c) x[c] = sv[(size_t)row * 192 + c * 64 + lane];

#pragma unroll
  for (int it = 0; it < 4; ++it) {
    float4 xn[3];
    if (it < 3) {
#pragma unroll
      for (int c = 0; c < 3; ++c)
        xn[c] = sv[(size_t)(row + 1) * 192 + c * 64 + lane];
    }
    float a0 = 0.f, a1 = 0.f, a2 = 0.f, a3 = 0.f;
#pragma unroll
    for (int c = 0; c < 3; ++c) {
      a0 = fmaf(x[c].x, w[0][c].x, a0); a0 = fmaf(x[c].y, w[0][c].y, a0);
      a0 = fmaf(x[c].z, w[0][c].z, a0); a0 = fmaf(x[c].w, w[0][c].w, a0);
      a1 = fmaf(x[c].x, w[1][c].x, a1); a1 = fmaf(x[c].y, w[1][c].y, a1);
      a1 = fmaf(x[c].z, w[1][c].z, a1); a1 = fmaf(x[c].w, w[1][c].w, a1);
      a2 = fmaf(x[c].x, w[2][c].x, a2); a2 = fmaf(x[c].y, w[2][c].y, a2);
      a2 = fmaf(x[c].z, w[2][c].z, a2); a2 = fmaf(x[c].w, w[2][c].w, a2);
      a3 = fmaf(x[c].x, w[3][c].x, a3); a3 = fmaf(x[c].y, w[3][c].y, a3);
      a3 = fmaf(x[c].z, w[3][c].z, a3); a3 = fmaf(x[c].w, w[3][c].w, a3);
    }
    // within-16 reduction: ror4, ror8, quad xor1 (0xB1), quad xor2 (0x4E)
#define RED16(a)                                                   \
    a += dppf<0x124>(a); a += dppf<0x128>(a);                      \
    a += dppf<0xB1>(a);  a += dppf<0x4E>(a);
    RED16(a0) RED16(a1) RED16(a2) RED16(a3)
#undef RED16
    a0 += __shfl_xor(a0, 16); a0 += __shfl_xor(a0, 32);
    a1 += __shfl_xor(a1, 16); a1 += __shfl_xor(a1, 32);
    a2 += __shfl_xor(a2, 16); a2 += __shfl_xor(a2, 32);
    a3 += __shfl_xor(a3, 16); a3 += __shfl_xor(a3, 32);
    if (lane == 0) {
      float4 o; o.x = a0 + bb.x; o.y = a1 + bb.y; o.z = a2 + bb.z; o.w = a3 + bb.w;
      ((float4*)emis)[row] = o;
    }
    row += 1;
#pragma unroll
    for (int c = 0; c < 3; ++c) x[c] = xn[c];
  }
}

// ---------------------------------------------------------------------------
// Kernel 2: Viterbi per batch. 1 wave per block. Emissions staged to LDS
// up-front (8 KB); chain reads only LDS. Backpointers computed on-chain
// (parallel cmp/cndmask off the max path), packed 2 bits/step in a register,
// flushed 1 uint32 per 8-step chunk. Backtrack via 2-bit map-composition
// suffix scan (verified in R2).
// ---------------------------------------------------------------------------

// compose packed 2-bit maps: h(x) = f(g(x))
__device__ __forceinline__ uint32_t map_compose(uint32_t f, uint32_t g) {
  uint32_t h = 0;
#pragma unroll
  for (int x = 0; x < 4; ++x) {
    uint32_t gx = (g >> (2 * x)) & 3u;
    uint32_t fx = (f >> (2 * gx)) & 3u;
    h |= fx << (2 * x);
  }
  return h;
}

__global__ __launch_bounds__(64) void viterbi_kernel(
    const float* __restrict__ emis, const float* __restrict__ trans,
    const float* __restrict__ startT, const float* __restrict__ endT,
    int* __restrict__ out) {
  const int b    = blockIdx.x;
  const int lane = threadIdx.x;          // 0..63
  const int j    = lane & 3;

  __shared__ float4 em4[TT];             // emissions [t][0..3], 8 KB
  __shared__ uint32_t bpw[64][4];        // packed bp: chunk c, state j
  float* em = (float*)em4;

  // ---- stage emissions: 512 float4, 8 per lane, fully coalesced ----
  const float4* ev = (const float4*)(emis + (size_t)b * (TT * 4));
  float4 stg[8];
#pragma unroll
  for (int q = 0; q < 8; ++q) stg[q] = ev[q * 64 + lane];
#pragma unroll
  for (int q = 0; q < 8; ++q) em4[q * 64 + lane] = stg[q];

  const float tr0 = trans[0 * 4 + j];
  const float tr1 = trans[1 * 4 + j];
  const float tr2 = trans[2 * 4 + j];
  const float tr3 = trans[3 * 4 + j];
  const float endj = endT[j];
  const float s0j  = startT[j];

  __syncthreads();

  float s = s0j + em[j];                 // t = 0
  const bool store_lane = (lane < 4);

  uint32_t acc;
  auto step = [&](float e, int q) {
    float v0 = dppf<0x00>(s);            // s_prev[0] broadcast in quad
    float v1 = dppf<0x55>(s);
    float v2 = dppf<0xAA>(s);
    float v3 = dppf<0xFF>(s);
    float c0 = v0 + tr0;
    float c1 = v1 + tr1;
    float c2 = v2 + tr2;
    float c3 = v3 + tr3;
    float m01 = fmaxf(c0, c1); uint32_t b01 = (c1 > c0) ? 1u : 0u;
    float m23 = fmaxf(c2, c3); uint32_t b23 = (c3 > c2) ? 3u : 2u;
    float m   = fmaxf(m01, m23);
    uint32_t bi = (m23 > m01) ? b23 : b01;   // lowest-index tie-break
    s = m + e;
    acc |= bi << (2 * q);
  };

  float ebuf[8];
#pragma unroll
  for (int q = 0; q < 8; ++q) ebuf[q] = em[(1 + q) * 4 + j];

  for (int c = 0; c < 63; ++c) {         // chunks: t = 8c+1 .. 8c+8
    float enext[8];
    const int base = 8 * c + 9;
#pragma unroll
    for (int q = 0; q < 8; ++q) {
      int tt = base + q; if (tt > 511) tt = 511;
      enext[q] = em[tt * 4 + j];
    }
    acc = 0;
#pragma unroll
    for (int q = 0; q < 8; ++q) step(ebuf[q], q);
    if (store_lane) bpw[c][j] = acc;
#pragma unroll
    for (int q = 0; q < 8; ++q) ebuf[q] = enext[q];
  }
  {                                       // tail chunk: t = 505..511
    acc = 0;
#pragma unroll
    for (int q = 0; q < 7; ++q) step(ebuf[q], q);
    if (store_lane) bpw[63][j] = acc;
  }

  // final argmax, exact lowest-index tie-break (all lanes agree)
  float f = s + endj;
  int best_last;
  {
    float f0 = dppf<0x00>(f);
    float f1 = dppf<0x55>(f);
    float f2 = dppf<0xAA>(f);
    float f3 = dppf<0xFF>(f);
    float bm = f0; int bi = 0;
    if (f1 > bm) { bm = f1; bi = 1; }
    if (f2 > bm) { bm = f2; bi = 2; }
    if (f3 > bm) { bm = f3; bi = 3; }
    best_last = bi;
  }

  __syncthreads();

  // ---- backtrack: lane l owns steps s in [8l+1, 8l+8] (= chunk l) ----
  const uint32_t w0 = bpw[lane][0];
  const uint32_t w1 = bpw[lane][1];
  const uint32_t w2 = bpw[lane][2];
  const uint32_t w3 = bpw[lane][3];

  const int lo = 8 * lane + 1;
  uint32_t g[8];
  uint32_t A = 0xE4;                     // identity map
#pragma unroll
  for (int q = 7; q >= 0; --q) {
    const int sq = lo + q;
    uint32_t mq = 0xE4;
    if (sq <= 511) {
      mq = ((w0 >> (2 * q)) & 3u) | (((w1 >> (2 * q)) & 3u) << 2) |
           (((w2 >> (2 * q)) & 3u) << 4) | (((w3 >> (2 * q)) & 3u) << 6);
    }
    g[q] = mq;
    A = map_compose(mq, A);              // later steps applied first
  }

  // inclusive suffix scan across lanes: V_l = G_l ∘ G_{l+1} ∘ ... ∘ G_63
  uint32_t V = A;
#pragma unroll
  for (int d = 1; d < 64; d <<= 1) {
    uint32_t o = __shfl_down(V, d);
    if (lane + d < 64) V = map_compose(V, o);
  }
  uint32_t S = __shfl_down(V, 1);        // exclusive (chunks above this lane)
  if (lane == 63) S = 0xE4;

  int cur = (int)((S >> (2 * best_last)) & 3u);   // tag at position hi
  const int hi = min(lo + 7, 511);
  int* ob = out + b * TT;
  ob[hi] = cur;
#pragma unroll
  for (int q = 7; q >= 0; --q) {
    const int sq = lo + q;
    if (sq <= 511) {
      cur = (int)((g[q] >> (2 * cur)) & 3u);
      ob[sq - 1] = cur;
    }
  }
}

extern "C" void kernel_launch(void* const* d_in, const int* in_sizes, int n_in,
                              void* d_out, int out_size, void* d_ws, size_t ws_size,
                              hipStream_t stream) {
  const float* sent   = (const float*)d_in[0];  // [B,T,H]
  const float* W      = (const float*)d_in[1];  // [K,H]
  const float* bias   = (const float*)d_in[2];  // [K]
  const float* startT = (const float*)d_in[3];  // [K]
  const float* endT   = (const float*)d_in[4];  // [K]
  const float* trans  = (const float*)d_in[5];  // [K,K]
  float* emis = (float*)d_ws;                   // [B,T,K] = 512 KB scratch
  int* outp   = (int*)d_out;                    // [B,T] int32

  emis_kernel<<<2048, 256, 0, stream>>>(sent, W, bias, emis);
  viterbi_kernel<<<BB, 64, 0, stream>>>(emis, trans, startT, endT, outp);
}